// Round 1
// baseline (403.377 us; speedup 1.0000x reference)
//
#include <hip/hip_runtime.h>

#define N_NODES 10000
#define DEG 32
#define HIDDEN 128
#define N_EDGES (N_NODES * DEG)

// Kernel 1: per-node dual dot products.
// a[i] = sum_k h[i][k] * W[k]         (k = 0..127)
// c[i] = sum_k h[i][k] * W[128 + k]
// One wave (64 lanes) per node; lane l covers k=l and k=l+64.
__global__ __launch_bounds__(256) void node_dots(
    const float* __restrict__ h, const float* __restrict__ W,
    float* __restrict__ a, float* __restrict__ c) {
    int wave = (blockIdx.x * blockDim.x + threadIdx.x) >> 6;
    int lane = threadIdx.x & 63;
    if (wave >= N_NODES) return;
    const float* hr = h + (size_t)wave * HIDDEN;
    float h0 = hr[lane];
    float h1 = hr[lane + 64];
    float pa = h0 * W[lane]          + h1 * W[lane + 64];
    float pc = h0 * W[HIDDEN + lane] + h1 * W[HIDDEN + lane + 64];
    #pragma unroll
    for (int off = 32; off > 0; off >>= 1) {
        pa += __shfl_down(pa, off);
        pc += __shfl_down(pc, off);
    }
    if (lane == 0) {
        a[wave] = pa;
        c[wave] = pc;
    }
}

// Kernel 2: zero the dense 10000x10000 output (400 MB) with float4 stores.
__global__ __launch_bounds__(256) void zero_out(float4* __restrict__ out, long n4) {
    long i = (long)blockIdx.x * blockDim.x + threadIdx.x;
    long stride = (long)gridDim.x * blockDim.x;
    float4 z = make_float4(0.f, 0.f, 0.f, 0.f);
    for (; i < n4; i += stride) out[i] = z;
}

// Kernel 3: scatter edge scores. One thread per edge.
__global__ __launch_bounds__(256) void scatter_k(
    const int* __restrict__ src, const int* __restrict__ dst,
    const float* __restrict__ weight,
    const float* __restrict__ a, const float* __restrict__ c,
    const float* __restrict__ W, const float* __restrict__ b,
    float* __restrict__ out) {
    int e = blockIdx.x * blockDim.x + threadIdx.x;
    if (e >= N_EDGES) return;
    int s = src[e];
    int d = dst[e];
    float score = a[s] + c[d] + weight[e] * W[2 * HIDDEN] + b[0];
    out[(size_t)s * N_NODES + d] = score;
}

extern "C" void kernel_launch(void* const* d_in, const int* in_sizes, int n_in,
                              void* d_out, int out_size, void* d_ws, size_t ws_size,
                              hipStream_t stream) {
    const float* h      = (const float*)d_in[0];
    const int*   src    = (const int*)d_in[1];
    const int*   dst    = (const int*)d_in[2];
    const float* weight = (const float*)d_in[3];
    const float* W      = (const float*)d_in[4];
    const float* b      = (const float*)d_in[5];
    float* out = (float*)d_out;

    float* a = (float*)d_ws;            // N_NODES floats
    float* c = a + N_NODES;             // N_NODES floats

    // 1) per-node dots: 10000 waves, 4 waves/block -> 2500 blocks
    node_dots<<<(N_NODES + 3) / 4, 256, 0, stream>>>(h, W, a, c);

    // 2) zero the 100M-element output: 25M float4, grid-stride
    long n4 = (long)N_NODES * N_NODES / 4;
    zero_out<<<8192, 256, 0, stream>>>((float4*)out, n4);

    // 3) scatter 320k edge scores
    scatter_k<<<(N_EDGES + 255) / 256, 256, 0, stream>>>(
        src, dst, weight, a, c, W, b, out);
}